// Round 6
// baseline (179464.331 us; speedup 1.0000x reference)
//
#include <hip/hip_runtime.h>
#include <hip/hip_bf16.h>
#include <math.h>

// ---------------------------------------------------------------------------
// VRNN on MI355X — Round 6: persistent sequential phase with device barriers.
// R3/R5 lesson: per-step kernel launches (4-6 x 256 steps) pay launch+drain+
// cold-latency every stage -> 88-170us/step. Fix: ONE kernel per chunk, 512
// WGs x 256 thr (<=2/CU, co-residency guaranteed), agent-scope sense barrier
// between column-split stages. h kept in registers of its owning WG across
// all steps. phi_x partials for enc1 AND GRU hoisted into one packed
// per-chunk GEMM (PEG = [PE1 | GXX], N=2048). NT stores for activations to
// keep barrier L2-writeback cheap. Pre/post phases: R5's gemm512 MFMA path.
// ---------------------------------------------------------------------------

typedef __attribute__((ext_vector_type(8))) short bfrag;   // 8 x bf16
typedef __attribute__((ext_vector_type(4))) float ffrag;   // 4 x f32
typedef __hip_bfloat16 bf16;

#define MFMA16(a,b,c) __builtin_amdgcn_mfma_f32_16x16x32_bf16(a, b, c, 0, 0, 0)
#define NWG 512

__device__ __forceinline__ float softplus_f(float v) {
    return (v > 20.f) ? v : log1pf(expf(v));
}
__device__ __forceinline__ float sigmoid_f(float v) {
    return 1.f / (1.f + expf(-v));
}
__device__ __forceinline__ void nts_f(float* p, float v) {
    __builtin_nontemporal_store(v, p);
}
__device__ __forceinline__ void nts_b(bf16* p, float v) {
    bf16 h = __float2bfloat16(v);
    __builtin_nontemporal_store(*(short*)&h, (short*)p);
}

// device-wide sense barrier (bar[0]=count, bar[1]=generation)
__device__ __forceinline__ void gbar(int* bar) {
    __threadfence();
    __syncthreads();
    if (threadIdx.x == 0) {
        int g = __hip_atomic_load(bar + 1, __ATOMIC_RELAXED, __HIP_MEMORY_SCOPE_AGENT);
        if (__hip_atomic_fetch_add(bar, 1, __ATOMIC_ACQ_REL, __HIP_MEMORY_SCOPE_AGENT) == NWG - 1) {
            __hip_atomic_store(bar, 0, __ATOMIC_RELAXED, __HIP_MEMORY_SCOPE_AGENT);
            __hip_atomic_fetch_add(bar + 1, 1, __ATOMIC_RELEASE, __HIP_MEMORY_SCOPE_AGENT);
        } else {
            while (__hip_atomic_load(bar + 1, __ATOMIC_ACQUIRE, __HIP_MEMORY_SCOPE_AGENT) == g)
                __builtin_amdgcn_s_sleep(8);
        }
    }
    __syncthreads();
    __threadfence();
}

// ---- setup converters ----
__global__ __launch_bounds__(256) void f2b_kernel(
    const float* __restrict__ s, bf16* __restrict__ d, int n)
{
    int i = blockIdx.x * 256 + threadIdx.x;
    if (i < n) d[i] = __float2bfloat16(s[i]);
}
__global__ __launch_bounds__(256) void f2bs_kernel(
    const float* __restrict__ s, int sld, int soff,
    bf16* __restrict__ d, int dld, int rows, int cols)
{
    int i = blockIdx.x * 256 + threadIdx.x;
    if (i < rows * cols) {
        int r = i / cols, c = i - r * cols;
        d[(size_t)r * dld + c] = __float2bfloat16(s[(size_t)r * sld + soff + c]);
    }
}
__global__ __launch_bounds__(256) void fcopy_kernel(
    const float* __restrict__ s, float* __restrict__ d, int n)
{
    int i = blockIdx.x * 256 + threadIdx.x;
    if (i < n) d[i] = s[i];
}
__global__ __launch_bounds__(256) void init_kernel(
    float* __restrict__ hprev, float* __restrict__ out, int* __restrict__ bar)
{
    const int idx = blockIdx.x * 256 + threadIdx.x;
    if (idx < 262144) hprev[idx] = 0.f;
    if (idx < 3) out[idx] = 0.f;
    if (idx < 2) bar[idx] = 0;
}

// ---------------------------------------------------------------------------
// gemm512: C[M,N] = act(bias + sum_s A_s @ W_s^T). 512 thr, tile 128x128.
// act: 0 none, 1 relu, 3 relu on col<64 only.
// ---------------------------------------------------------------------------
__global__ __launch_bounds__(512) void gemm512(
    const bf16* __restrict__ A0, int lda0, const bf16* __restrict__ W0, int ldw0, int K0,
    const bf16* __restrict__ A1, int lda1, const bf16* __restrict__ W1, int ldw1, int K1,
    const float* __restrict__ bias, int act,
    void* __restrict__ C, int ldc, int obf)
{
    const int tid = threadIdx.x;
    const int L = tid & 63, w = tid >> 6;
    const int m0 = blockIdx.y * 128 + (w & 1) * 64;
    const int n0 = blockIdx.x * 128 + (w >> 1) * 32;
    const int lr = L & 15;
    const int qk = L >> 4;
    const int lk = qk * 8;

    ffrag acc[4][2];
#pragma unroll
    for (int i = 0; i < 4; ++i)
#pragma unroll
        for (int j = 0; j < 2; ++j)
#pragma unroll
            for (int r = 0; r < 4; ++r) acc[i][j][r] = 0.f;

    for (int s = 0; s < 2; ++s) {
        const bf16* A = s ? A1 : A0;
        if (!A) break;
        const bf16* W = s ? W1 : W0;
        const int lda = s ? lda1 : lda0;
        const int ldw = s ? ldw1 : ldw0;
        const int K   = s ? K1 : K0;
        const bf16* ap = A + (size_t)(m0 + lr) * lda + lk;
        const bf16* bp = W + (size_t)(n0 + lr) * ldw + lk;
        for (int k0 = 0; k0 < K; k0 += 32) {
            bfrag a[4], b[2];
#pragma unroll
            for (int i = 0; i < 4; ++i)
                a[i] = *(const bfrag*)(ap + (size_t)(16 * i) * lda + k0);
#pragma unroll
            for (int j = 0; j < 2; ++j)
                b[j] = *(const bfrag*)(bp + (size_t)(16 * j) * ldw + k0);
#pragma unroll
            for (int i = 0; i < 4; ++i)
#pragma unroll
                for (int j = 0; j < 2; ++j)
                    acc[i][j] = MFMA16(a[i], b[j], acc[i][j]);
        }
    }

#pragma unroll
    for (int i = 0; i < 4; ++i)
#pragma unroll
    for (int j = 0; j < 2; ++j)
#pragma unroll
    for (int r = 0; r < 4; ++r) {
        const int row = m0 + 16 * i + qk * 4 + r;
        const int col = n0 + 16 * j + lr;
        float v = acc[i][j][r];
        if (bias) v += bias[col];
        if (act == 1) v = fmaxf(v, 0.f);
        else if (act == 3) { if (col < 64) v = fmaxf(v, 0.f); }
        const size_t g = (size_t)row * ldc + col;
        if (obf) ((bf16*)C)[g] = __float2bfloat16(v);
        else     ((float*)C)[g] = v;
    }
}

// 64x64-tile GEMM for N=64 (pms). act 2 = softplus on col>=32.
__global__ __launch_bounds__(256) void mfma_gemm(
    const bf16* __restrict__ A0, int lda0, const bf16* __restrict__ W0, int ldw0, int K0,
    const float* __restrict__ bias, int act,
    void* __restrict__ C, int ldc, int obf)
{
    const int tid = threadIdx.x;
    const int L = tid & 63, w = tid >> 6;
    const int m0 = blockIdx.y * 64 + (w & 1) * 32;
    const int n0 = blockIdx.x * 64 + (w >> 1) * 32;
    const int lr = L & 15;
    const int lk = (L >> 4) * 8;

    ffrag acc[2][2];
#pragma unroll
    for (int i = 0; i < 2; ++i)
#pragma unroll
        for (int j = 0; j < 2; ++j)
#pragma unroll
            for (int r = 0; r < 4; ++r) acc[i][j][r] = 0.f;

    const bf16* a0p = A0 + (size_t)(m0 + lr) * lda0 + lk;
    const bf16* a1p = a0p + (size_t)16 * lda0;
    const bf16* b0p = W0 + (size_t)(n0 + lr) * ldw0 + lk;
    const bf16* b1p = b0p + (size_t)16 * ldw0;
    for (int k0 = 0; k0 < K0; k0 += 32) {
        bfrag a0 = *(const bfrag*)(a0p + k0);
        bfrag a1 = *(const bfrag*)(a1p + k0);
        bfrag b0 = *(const bfrag*)(b0p + k0);
        bfrag b1 = *(const bfrag*)(b1p + k0);
        acc[0][0] = MFMA16(a0, b0, acc[0][0]);
        acc[0][1] = MFMA16(a0, b1, acc[0][1]);
        acc[1][0] = MFMA16(a1, b0, acc[1][0]);
        acc[1][1] = MFMA16(a1, b1, acc[1][1]);
    }

#pragma unroll
    for (int i = 0; i < 2; ++i)
#pragma unroll
    for (int j = 0; j < 2; ++j)
#pragma unroll
    for (int r = 0; r < 4; ++r) {
        const int row = m0 + 16 * i + (L >> 4) * 4 + r;
        const int col = n0 + 16 * j + lr;
        float v = acc[i][j][r];
        if (bias) v += bias[col];
        if (act == 1) v = fmaxf(v, 0.f);
        else if (act == 2) { if (col >= 32) v = softplus_f(v); }
        const size_t g = (size_t)row * ldc + col;
        if (obf) ((bf16*)C)[g] = __float2bfloat16(v);
        else     ((float*)C)[g] = v;
    }
}

// ---------------------------------------------------------------------------
// seq_persist: whole sequential phase of one chunk, ONE launch, 512 WGs.
// Stages per t: A enc1+gh | B enc2 | C ms | D z+phiz | E gz+gates.
// ---------------------------------------------------------------------------
__global__ __launch_bounds__(256, 2) void seq_persist(
    const bf16* __restrict__ PEG,    // [TC*512,2048] = PE1 | GXX
    const float* __restrict__ epsC,  // [TC*512,32]
    const bf16* __restrict__ WA,     // [2048,512] = W1B rows | Whh rows
    const bf16* __restrict__ W2,     // [512,512]
    const bf16* __restrict__ MSW,    // [64,512]
    const bf16* __restrict__ PZW,    // [512,32]
    const bf16* __restrict__ WZ,     // [1536,512] = WihZ
    const float* __restrict__ eb1, const float* __restrict__ eb2,
    const float* __restrict__ msb, const float* __restrict__ pzb,
    float* __restrict__ HPREV,       // [512,512]
    bf16* __restrict__ E1,           // [512,512]
    bf16* __restrict__ ENCH,         // [512,512]
    float* __restrict__ GH,          // [512,1536]
    float* __restrict__ EMSC,        // [TC*512,64]
    bf16* __restrict__ PHIZC,        // [TC*512,512]
    bf16* __restrict__ HH,           // [(TC+1)*512,512]
    int* __restrict__ bar, int TC)
{
    __shared__ __align__(16) float SM[3072];   // 12KB scratch (C/D/E union)
    const int wg = blockIdx.x;
    const int tid = threadIdx.x;
    const int L = tid & 63, w = tid >> 6;
    const int lr = L & 15, qk = L >> 4, lk = qk * 8;

    const int rgA = wg >> 5, clA = wg & 31;    // A: rows rgA*32, cols clA*64/2048
    const int rgB = wg >> 4, clB = wg & 15;    // B(wg<256): rows*32, cols*32
    const int rgC = wg >> 2, clC = wg & 3;     // C(wg<128): rows*16, cols*16
    const int rgD = wg >> 5, clD = wg & 31;    // D: rows*32, phiz cols*16
    const int rgE = wg >> 5, clE = wg & 31;    // E: rows*32, h cols*16
    const int erl = tid >> 4, ecl = tid & 15;  // E epilogue (row,col) in tile

    // prologue: hRF from HPREV; HH[0] = bf16(h)
    float hRF[2];
#pragma unroll
    for (int rt = 0; rt < 2; ++rt) {
        const int row = rgE * 32 + rt * 16 + erl;
        const int col = clE * 16 + ecl;
        const float hv = HPREV[(size_t)row * 512 + col];
        hRF[rt] = hv;
        nts_b(HH + (size_t)row * 512 + col, hv);
    }
    gbar(bar);

    for (int t = 0; t < TC; ++t) {
        const size_t tb = (size_t)t * 512;

        // ---- A: enc1 (cols<512, +PE1+eb1, relu) and gh (cols>=512) ----
        {
            const bf16* hbase = HH + tb * 512;
            const int r0 = rgA * 32 + (w & 1) * 16;
            const int c0 = clA * 64 + (w >> 1) * 32;
            const bf16* ap = hbase + (size_t)(r0 + lr) * 512 + lk;
            const bf16* bp = WA + (size_t)(c0 + lr) * 512 + lk;
            ffrag ac0, ac1;
#pragma unroll
            for (int r = 0; r < 4; ++r) { ac0[r] = 0.f; ac1[r] = 0.f; }
            for (int k0 = 0; k0 < 512; k0 += 32) {
                bfrag av = *(const bfrag*)(ap + k0);
                bfrag b0 = *(const bfrag*)(bp + k0);
                bfrag b1 = *(const bfrag*)(bp + 16 * 512 + k0);
                ac0 = MFMA16(av, b0, ac0);
                ac1 = MFMA16(av, b1, ac1);
            }
#pragma unroll
            for (int j = 0; j < 2; ++j)
#pragma unroll
            for (int r = 0; r < 4; ++r) {
                const int row = r0 + qk * 4 + r;
                const int col = c0 + j * 16 + lr;
                float v = j ? ac1[r] : ac0[r];
                if (col < 512) {
                    v += eb1[col] + __bfloat162float(PEG[(tb + row) * 2048 + col]);
                    nts_b(E1 + (size_t)row * 512 + col, fmaxf(v, 0.f));
                } else {
                    nts_f(GH + (size_t)row * 1536 + (col - 512), v);
                }
            }
        }
        gbar(bar);

        // ---- B: enc2 (wg<256) ----
        if (wg < 256) {
            const int r0 = rgB * 32 + (w & 1) * 16;
            const int c0 = clB * 32 + (w >> 1) * 16;
            const bf16* ap = E1 + (size_t)(r0 + lr) * 512 + lk;
            const bf16* bp = W2 + (size_t)(c0 + lr) * 512 + lk;
            ffrag acc;
#pragma unroll
            for (int r = 0; r < 4; ++r) acc[r] = 0.f;
            for (int k0 = 0; k0 < 512; k0 += 32) {
                bfrag av = *(const bfrag*)(ap + k0);
                bfrag bv = *(const bfrag*)(bp + k0);
                acc = MFMA16(av, bv, acc);
            }
#pragma unroll
            for (int r = 0; r < 4; ++r) {
                const int row = r0 + qk * 4 + r;
                const int col = c0 + lr;
                nts_b(ENCH + (size_t)row * 512 + col, fmaxf(acc[r] + eb2[col], 0.f));
            }
        }
        gbar(bar);

        // ---- C: ms (wg<128), K split 4 ways over waves, LDS reduce ----
        if (wg < 128) {
            const bf16* ap = ENCH + (size_t)(rgC * 16 + lr) * 512 + w * 128 + lk;
            const bf16* bp = MSW + (size_t)(clC * 16 + lr) * 512 + w * 128 + lk;
            ffrag acc;
#pragma unroll
            for (int r = 0; r < 4; ++r) acc[r] = 0.f;
#pragma unroll
            for (int k0 = 0; k0 < 128; k0 += 32) {
                bfrag av = *(const bfrag*)(ap + k0);
                bfrag bv = *(const bfrag*)(bp + k0);
                acc = MFMA16(av, bv, acc);
            }
#pragma unroll
            for (int r = 0; r < 4; ++r)
                SM[(w * 16 + qk * 4 + r) * 16 + lr] = acc[r];
        }
        __syncthreads();
        if (wg < 128) {
            const int rl = tid >> 4, c = tid & 15;
            float s = SM[(0 + rl) * 16 + c] + SM[(16 + rl) * 16 + c]
                    + SM[(32 + rl) * 16 + c] + SM[(48 + rl) * 16 + c];
            const int col = clC * 16 + c;
            s += msb[col];
            if (col >= 32) s = softplus_f(s);
            nts_f(EMSC + (tb + rgC * 16 + rl) * 64 + col, s);
        }
        gbar(bar);

        // ---- D: z + phiz ----
        {
            bf16* zb = (bf16*)SM;   // [32][32]
            const int zr = tid >> 3, zc0 = (tid & 7) * 4;
#pragma unroll
            for (int e = 0; e < 4; ++e) {
                const int c = zc0 + e;
                const int row = rgD * 32 + zr;
                const float mean = EMSC[(tb + row) * 64 + c];
                const float sd   = EMSC[(tb + row) * 64 + 32 + c];
                const float ev   = epsC[(tb + row) * 32 + c];
                float zv = ev * sd + mean;
                if (c < 4) zv *= 10.f;
                zb[zr * 32 + c] = __float2bfloat16(zv);
            }
            __syncthreads();
            if (w < 2) {
                bfrag av = *(const bfrag*)(zb + (w * 16 + lr) * 32 + lk);
                bfrag bv = *(const bfrag*)(PZW + (size_t)(clD * 16 + lr) * 32 + lk);
                ffrag acc;
#pragma unroll
                for (int r = 0; r < 4; ++r) acc[r] = 0.f;
                acc = MFMA16(av, bv, acc);
#pragma unroll
                for (int r = 0; r < 4; ++r) {
                    const int row = rgD * 32 + w * 16 + qk * 4 + r;
                    const int col = clD * 16 + lr;
                    nts_b(PHIZC + (tb + row) * 512 + col,
                          fmaxf(acc[r] + pzb[col], 0.f));
                }
            }
        }
        gbar(bar);

        // ---- E: gz (K split 2) + gates -> h ----
        {
            const int ks = w & 1, rt = w >> 1;
            const bf16* ap = PHIZC + (tb + rgE * 32 + rt * 16 + lr) * 512 + ks * 256 + lk;
            const bf16* bp = WZ + (size_t)(clE * 16 + lr) * 512 + ks * 256 + lk;
            ffrag g0, g1, g2;
#pragma unroll
            for (int r = 0; r < 4; ++r) { g0[r] = 0.f; g1[r] = 0.f; g2[r] = 0.f; }
#pragma unroll
            for (int k0 = 0; k0 < 256; k0 += 32) {
                bfrag av = *(const bfrag*)(ap + k0);
                bfrag b0 = *(const bfrag*)(bp + k0);
                bfrag b1 = *(const bfrag*)(bp + (size_t)512 * 512 + k0);
                bfrag b2 = *(const bfrag*)(bp + (size_t)1024 * 512 + k0);
                g0 = MFMA16(av, b0, g0);
                g1 = MFMA16(av, b1, g1);
                g2 = MFMA16(av, b2, g2);
            }
            float* EL = SM;   // [(ks*2+rt)*3+g][16][16]
            const int bslot = (ks * 2 + rt) * 3;
#pragma unroll
            for (int r = 0; r < 4; ++r) {
                EL[((bslot + 0) * 16 + qk * 4 + r) * 16 + lr] = g0[r];
                EL[((bslot + 1) * 16 + qk * 4 + r) * 16 + lr] = g1[r];
                EL[((bslot + 2) * 16 + qk * 4 + r) * 16 + lr] = g2[r];
            }
        }
        __syncthreads();
        {
#pragma unroll
            for (int rt2 = 0; rt2 < 2; ++rt2) {
                const int row = rgE * 32 + rt2 * 16 + erl;
                const int j = clE * 16 + ecl;
                float gx[3], gh[3];
#pragma unroll
                for (int g = 0; g < 3; ++g) {
                    const float gz =
                        SM[(((0 * 2 + rt2) * 3 + g) * 16 + erl) * 16 + ecl] +
                        SM[(((1 * 2 + rt2) * 3 + g) * 16 + erl) * 16 + ecl];
                    gx[g] = gz + __bfloat162float(PEG[(tb + row) * 2048 + 512 + g * 512 + j]);
                    gh[g] = GH[(size_t)row * 1536 + g * 512 + j];
                }
                const float rg = sigmoid_f(gx[0] + gh[0]);
                const float zg = sigmoid_f(gx[1] + gh[1]);
                const float nn = tanhf(gx[2] + rg * gh[2]);
                const float hnew = (1.f - zg) * nn + zg * hRF[rt2];
                hRF[rt2] = hnew;
                nts_b(HH + (tb + 512 + row) * 512 + j, hnew);
            }
        }
        gbar(bar);
    }

    // epilogue: chunk handoff
#pragma unroll
    for (int rt = 0; rt < 2; ++rt) {
        const int row = rgE * 32 + rt * 16 + erl;
        const int col = clE * 16 + ecl;
        HPREV[(size_t)row * 512 + col] = hRF[rt];
    }
}

// ---------------------------------------------------------------------------
// KLD + final (unchanged from R5)
// ---------------------------------------------------------------------------
__global__ __launch_bounds__(256) void kld_kernel(
    const float* __restrict__ emsc, const float* __restrict__ pms,
    float* __restrict__ out)
{
    const size_t p0 = (size_t)blockIdx.x * 1024 + threadIdx.x;
    float acc = 0.f;
#pragma unroll
    for (int rep = 0; rep < 4; ++rep) {
        const size_t p = p0 + (size_t)rep * 256;
        const size_t i = p >> 5; const int c = p & 31;
        const float m1 = emsc[i * 64 + c];
        const float s1 = fmaxf(emsc[i * 64 + 32 + c], 1e-9f);
        const float m2 = pms[i * 64 + c];
        const float s2 = fmaxf(pms[i * 64 + 32 + c], 1e-9f);
        const float dm = m1 - m2;
        acc += 2.f * (logf(s2) - logf(s1)) + (s1 * s1 + dm * dm) / (s2 * s2) - 1.f;
    }
    for (int off = 32; off > 0; off >>= 1) acc += __shfl_down(acc, off);
    __shared__ float tmp[4];
    if ((threadIdx.x & 63) == 0) tmp[threadIdx.x >> 6] = acc;
    __syncthreads();
    if (threadIdx.x == 0)
        atomicAdd(out + 1, 0.5f * (tmp[0] + tmp[1] + tmp[2] + tmp[3]));
}

__global__ __launch_bounds__(256) void final_kernel(
    const float* __restrict__ ddc,
    const float* __restrict__ W2, const float* __restrict__ b2,
    const float* __restrict__ x,
    float* __restrict__ sums, float* __restrict__ outDM)
{
    __shared__ float Dh[32][64];
    __shared__ float W2s[64][65];
    const int tid = threadIdx.x;
    const size_t r0 = (size_t)blockIdx.x * 32;

    for (int i = tid; i < 32 * 64; i += 256)
        Dh[i >> 6][i & 63] = ddc[(r0 + (i >> 6)) * 128 + (i & 63)];
    for (int i = tid; i < 64 * 64; i += 256) W2s[i >> 6][i & 63] = W2[i];
    __syncthreads();

    float rec = 0.f, nll = 0.f;
#pragma unroll
    for (int rep = 0; rep < 8; ++rep) {
        const int idx = rep * 256 + tid;
        const int r = idx >> 6, j = idx & 63;
        float acc = b2[j];
#pragma unroll 8
        for (int k = 0; k < 64; ++k) acc += Dh[r][k] * W2s[j][k];
        const size_t g = (r0 + r) * 64 + j;
        const float xv = x[g];
        const float sd = softplus_f(ddc[(r0 + r) * 128 + 64 + j]);
        outDM[g] = acc;
        const float d = xv - acc;
        rec += d * d;
        nll += logf(sd + 1e-5f) + 0.9189385332046727f + d * d / (2.f * sd * sd);
    }
    for (int off = 32; off > 0; off >>= 1) {
        rec += __shfl_down(rec, off);
        nll += __shfl_down(nll, off);
    }
    __shared__ float rr[4], nn[4];
    if ((tid & 63) == 0) { rr[tid >> 6] = rec; nn[tid >> 6] = nll; }
    __syncthreads();
    if (tid == 0) {
        atomicAdd(sums + 0, rr[0] + rr[1] + rr[2] + rr[3]);
        atomicAdd(sums + 2, nn[0] + nn[1] + nn[2] + nn[3]);
    }
}

// ---------------------------------------------------------------------------

static void g512(hipStream_t s, int M, int N,
                 const bf16* A0, int lda0, const bf16* W0, int ldw0, int K0,
                 const bf16* A1, int lda1, const bf16* W1, int ldw1, int K1,
                 const float* bias, int act, void* C, int ldc, int obf)
{
    dim3 g(N / 128, M / 128), b(512);
    hipLaunchKernelGGL(gemm512, g, b, 0, s,
                       A0, lda0, W0, ldw0, K0, A1, lda1, W1, ldw1, K1,
                       bias, act, C, ldc, obf);
}
static void f2bs(hipStream_t s, const float* src, int sld, int soff,
                 bf16* dst, int dld, int rows, int cols) {
    int n = rows * cols;
    hipLaunchKernelGGL(f2bs_kernel, dim3((n + 255) / 256), dim3(256), 0, s,
                       src, sld, soff, dst, dld, rows, cols);
}
static void f2b(hipStream_t s, const float* src, bf16* dst, int n) {
    hipLaunchKernelGGL(f2b_kernel, dim3((n + 255) / 256), dim3(256), 0, s, src, dst, n);
}
static void fcp(hipStream_t s, const float* src, float* dst, int n) {
    hipLaunchKernelGGL(fcopy_kernel, dim3((n + 255) / 256), dim3(256), 0, s, src, dst, n);
}

// bf16-weight element offsets within WB
#define O_WA   0
#define O_WPB  1048576
#define O_WZ   2097152
#define O_EW2  2883584
#define O_MSW  3145728
#define O_PZW  3178496
#define O_PXW1 3194880
#define O_PXW2 3227648
#define O_PRW  3489792
#define O_PMSW 3751936
#define O_DW1  3784704
#define O_DW2  4308992
#define O_DDW  4571136

static size_t ws_needed(int tc) {
    return 31819776ull + (size_t)tc * 4587520ull;
}

extern "C" void kernel_launch(void* const* d_in, const int* in_sizes, int n_in,
                              void* d_out, int out_size, void* d_ws, size_t ws_size,
                              hipStream_t stream)
{
    const float* x_in   = (const float*)d_in[0];
    const float* eps_in = (const float*)d_in[1];
    const float* pxW1 = (const float*)d_in[2];  const float* pxb1 = (const float*)d_in[3];
    const float* pxW2 = (const float*)d_in[4];  const float* pxb2 = (const float*)d_in[5];
    const float* pzW  = (const float*)d_in[6];  const float* pzb  = (const float*)d_in[7];
    const float* eW1  = (const float*)d_in[8];  const float* eb1  = (const float*)d_in[9];
    const float* eW2  = (const float*)d_in[10]; const float* eb2  = (const float*)d_in[11];
    const float* emW  = (const float*)d_in[12]; const float* emb  = (const float*)d_in[13];
    const float* esW  = (const float*)d_in[14]; const float* esb  = (const float*)d_in[15];
    const float* prW  = (const float*)d_in[16]; const float* prb  = (const float*)d_in[17];
    const float* pmW  = (const float*)d_in[18]; const float* pmb  = (const float*)d_in[19];
    const float* psW  = (const float*)d_in[20]; const float* psb  = (const float*)d_in[21];
    const float* dW1  = (const float*)d_in[22]; const float* db1  = (const float*)d_in[23];
    const float* dW2  = (const float*)d_in[24]; const float* db2  = (const float*)d_in[25];
    const float* dsW  = (const float*)d_in[26]; const float* dsb  = (const float*)d_in[27];
    const float* dmW1 = (const float*)d_in[28]; const float* dmb1 = (const float*)d_in[29];
    const float* dmW2 = (const float*)d_in[30]; const float* dmb2 = (const float*)d_in[31];
    const float* gWih = (const float*)d_in[32]; const float* gWhh = (const float*)d_in[33];

    float* out = (float*)d_out;
    char* ws = (char*)d_ws;

    int TC = 1;
    const int cands[9] = {256, 128, 64, 32, 16, 8, 4, 2, 1};
    for (int i = 0; i < 9; ++i)
        if (ws_needed(cands[i]) <= ws_size) { TC = cands[i]; break; }
    const int NCH = 256 / TC;

    // ---- workspace map (bytes) ----
    bf16*  WB    = (bf16*)(ws);                         // 9,273,344
    float* BB    = (float*)(ws + 9273344ull);           // 1,024
    bf16*  XBF   = (bf16*)(ws + 9274368ull);            // 16,777,216
    float* HPREV = (float*)(ws + 26051584ull);          // 1,048,576
    bf16*  E1    = (bf16*)(ws + 27100160ull);           // 524,288
    bf16*  ENCH  = (bf16*)(ws + 27624448ull);           // 524,288
    float* GH    = (float*)(ws + 28148736ull);          // 3,145,728
    int*   BAR   = (int*)(ws + 31294464ull);            // 1,024 (2 used)
    bf16*  HH    = (bf16*)(ws + 31295488ull);           // (TC+1)*524,288
    size_t off = 31295488ull + (size_t)(TC + 1) * 524288ull;
    bf16*  R1    = (bf16*)(ws + off); off += (size_t)TC * 524288ull;  // px1 / prior_h / dec_eh
    bf16*  SCRA  = (bf16*)(ws + off); off += (size_t)TC * 524288ull;  // phix / dec_h
    bf16*  PEG   = (bf16*)(ws + off); off += (size_t)TC * 2097152ull; // PE1|GXX
    bf16*  PHIZC = (bf16*)(ws + off); off += (size_t)TC * 524288ull;
    float* EMSC  = (float*)(ws + off); off += (size_t)TC * 131072ull;
    float* U     = (float*)(ws + off);                  // TC*262,144 (pms/ddc)

    // ---- setup: weight packing / conversion ----
    f2bs(stream, eW1, 1024, 512, WB + O_WA, 512, 512, 512);           // W1B
    f2b (stream, gWhh, WB + O_WA + 262144, 786432);                   // Whh
    f2bs(stream, eW1, 1024, 0, WB + O_WPB, 512, 512, 512);            // W1A
    f2bs(stream, gWih, 1024, 0, WB + O_WPB + 262144, 512, 1536, 512); // WihX
    f2bs(stream, gWih, 1024, 512, WB + O_WZ, 512, 1536, 512);         // WihZ
    f2b (stream, eW2,  WB + O_EW2,  262144);
    f2b (stream, emW,  WB + O_MSW,  16384);
    f2b (stream, esW,  WB + O_MSW + 16384, 16384);
    f2b (stream, pzW,  WB + O_PZW,  16384);
    f2b (stream, pxW1, WB + O_PXW1, 32768);
    f2b (stream, pxW2, WB + O_PXW2, 262144);
    f2b (stream, prW,  WB + O_PRW,  262144);
    f2b (stream, pmW,  WB + O_PMSW, 16384);
    f2b (stream, psW,  WB + O_PMSW + 16384, 16384);
    f2b (stream, dW1,  WB + O_DW1,  524288);
    f2b (stream, dW2,  WB + O_DW2,  262144);
    f2b (stream, dmW1, WB + O_DDW,  32768);
    f2b (stream, dsW,  WB + O_DDW + 32768, 32768);
    f2b (stream, x_in, XBF, 8388608);
    fcp (stream, emb,  BB + 0,   32);
    fcp (stream, esb,  BB + 32,  32);
    fcp (stream, pmb,  BB + 64,  32);
    fcp (stream, psb,  BB + 96,  32);
    fcp (stream, dmb1, BB + 128, 64);
    fcp (stream, dsb,  BB + 192, 64);

    hipLaunchKernelGGL(init_kernel, dim3(1024), dim3(256), 0, stream, HPREV, out, BAR);

    for (int c = 0; c < NCH; ++c) {
        const int cs = c * TC;
        const int MR = TC * 512;

        // ---- pre: phi_x MLP + packed (PE1|GXX) GEMM ----
        g512(stream, MR, 512, XBF + (size_t)cs * 32768, 64, WB + O_PXW1, 64, 64,
             nullptr, 0, nullptr, 0, 0, pxb1, 1, R1, 512, 1);
        g512(stream, MR, 512, R1, 512, WB + O_PXW2, 512, 512,
             nullptr, 0, nullptr, 0, 0, pxb2, 1, SCRA, 512, 1);
        g512(stream, MR, 2048, SCRA, 512, WB + O_WPB, 512, 512,
             nullptr, 0, nullptr, 0, 0, nullptr, 0, PEG, 2048, 1);

        // ---- sequential phase: ONE persistent launch ----
        hipLaunchKernelGGL(seq_persist, dim3(NWG), dim3(256), 0, stream,
                           PEG, eps_in + (size_t)cs * 16384,
                           WB + O_WA, WB + O_EW2, WB + O_MSW, WB + O_PZW, WB + O_WZ,
                           eb1, eb2, BB + 0, pzb,
                           HPREV, E1, ENCH, GH, EMSC, PHIZC, HH, BAR, TC);

        // ---- post: prior + KLD ----
        g512(stream, MR, 512, HH, 512, WB + O_PRW, 512, 512,
             nullptr, 0, nullptr, 0, 0, prb, 1, R1, 512, 1);
        {
            dim3 g(1, MR / 64), b(256);
            hipLaunchKernelGGL(mfma_gemm, g, b, 0, stream,
                               R1, 512, WB + O_PMSW, 512, 512, BB + 64, 2, U, 64, 0);
        }
        hipLaunchKernelGGL(kld_kernel, dim3(TC * 16), dim3(256), 0, stream,
                           EMSC, U, out);

        // ---- post: dec + NLL/rec ----
        g512(stream, MR, 512, PHIZC, 512, WB + O_DW1, 1024, 512,
             HH, 512, WB + O_DW1 + 512, 1024, 512, db1, 1, R1, 512, 1);
        g512(stream, MR, 512, R1, 512, WB + O_DW2, 512, 512,
             nullptr, 0, nullptr, 0, 0, db2, 1, SCRA, 512, 1);
        g512(stream, MR, 128, SCRA, 512, WB + O_DDW, 512, 512,
             nullptr, 0, nullptr, 0, 0, BB + 128, 3, U, 128, 0);
        hipLaunchKernelGGL(final_kernel, dim3(MR / 32), dim3(256), 0, stream,
                           U, dmW2, dmb2, x_in + (size_t)cs * 32768,
                           out, out + 3 + (size_t)cs * 32768);
    }
}